// Round 14
// baseline (345.203 us; speedup 1.0000x reference)
//
#include <hip/hip_runtime.h>

typedef unsigned short u16;
typedef unsigned int u32;
typedef __attribute__((ext_vector_type(4))) u16 u16x4;
typedef __attribute__((ext_vector_type(8))) u16 u16x8;
typedef __attribute__((ext_vector_type(4))) u32 u32x4;
typedef __attribute__((ext_vector_type(4))) float f32x4;
typedef __attribute__((ext_vector_type(8))) _Float16 h8;
typedef __attribute__((ext_vector_type(2))) _Float16 h2;
typedef __attribute__((ext_vector_type(2))) __fp16 fp16x2;  // cvt_pkrtz return type

#define DEV static __device__ __forceinline__

DEV u16 f2h(float f) {
  union { _Float16 h; u16 u; } v; v.h = (_Float16)f; return v.u;
}
DEV float h2f(u16 u) {
  union { u16 u; _Float16 h; } v; v.u = u; return (float)v.h;
}
DEV h2 u2h2(u32 x) { union { u32 u; h2 h; } v; v.u = x; return v.h; }
DEV u32 h22u(h2 x) { union { u32 u; h2 h; } v; v.h = x; return v.u; }
DEV u32 pk2u(fp16x2 x) { union { u32 u; fp16x2 h; } v; v.h = x; return v.u; }

DEV void gl_lds16(const void* g, void* l) {
  __builtin_amdgcn_global_load_lds(
      (const __attribute__((address_space(1))) unsigned int*)g,
      (__attribute__((address_space(3))) unsigned int*)l,
      16, 0, 0);
}

// ---------------- workspace layout (bytes) ----------------
static const size_t OFF_COST = 0;
static const size_t OFF_Y1   = 100663296u;
static const size_t OFF_Y2   = 134217728u;
static const size_t OFF_W1S  = 150994944u;
static const size_t OFF_W2S  = 151240704u;
static const size_t OFF_P1S  = 151281664u;   // f32 [256][64]
static const size_t OFF_P1Q  = 151412736u;
static const size_t OFF_P2S  = 151543808u;   // f32 [256][32]
static const size_t OFF_P2Q  = 151609344u;
static const size_t OFF_BN1  = 151674880u;
static const size_t OFF_BN2  = 151675392u;
static const size_t OFF_WDT  = 151675648u;   // f16 [16 tap][32 c]
static const size_t OFF_CNT  = 151676672u;   // u32 [2] last-block counters

// ---------------- cost volume + merged weight prep ----------------
// Prep (w1s/w2s/wdt reorder+f16, counter zeroing) is folded into this
// kernel's prologue: independent outputs, stream-ordered before conv1.
// Saves one kernel launch + gap.
__global__ __launch_bounds__(512, 4) void cv_cost(
    const float* __restrict__ lf, const float* __restrict__ rf,
    u16* __restrict__ cost,
    const float* __restrict__ w1, const float* __restrict__ w2,
    const float* __restrict__ wd,
    u16* __restrict__ w1s, u16* __restrict__ w2s, u16* __restrict__ wdt,
    u32* __restrict__ cnt)
{
  __shared__ __align__(16) u32 smem[16 * 256 + 16 * 272];  // lfp | rfp
  u32* lfp = smem;
  u32* rfp = smem + 16 * 256;

  const int tid = threadIdx.x;
  const int lane = tid & 63, q = tid >> 6;   // q in 0..7
  const int h = blockIdx.x, b = blockIdx.y;

  // ---- merged prep ----
  {
    int gidx = (blockIdx.y * 128 + blockIdx.x) * 512 + tid;
    if (gidx < 122880) {
      int k = gidx & 31, o = (gidx >> 5) & 63;
      int s = (gidx >> 11) % 5, cg = (gidx >> 11) / 5;
      int slot = k >> 4, dc = k & 15;
      int tap = 2 * s + slot;
      float v = 0.f;
      if (tap < 9) {
        int kh = tap / 3, kw = tap % 3;
        int c = cg * 16 + dc;
        v = w1[((o * 192 + c) * 3 + kh) * 3 + kw];
      }
      w1s[gidx] = f2h(v);
    }
    if (gidx < 20480) {
      int k = gidx & 31, o = (gidx >> 5) & 31;
      int s = (gidx >> 10) % 5, cg = (gidx >> 10) / 5;
      int slot = k >> 4, dc = k & 15;
      int tap = 2 * s + slot;
      float v = 0.f;
      if (tap < 9) {
        int kh = tap / 3, kw = tap % 3;
        int c = cg * 16 + dc;
        v = w2[((o * 64 + c) * 3 + kh) * 3 + kw];
      }
      w2s[gidx] = f2h(v);
    }
    if (gidx < 512) {
      int tap = gidx >> 5, c = gidx & 31;    // wdt[tap][c] = wd[c][tap]
      wdt[gidx] = f2h(wd[c * 16 + tap]);
    }
    if (gidx == 0) { cnt[0] = 0u; cnt[1] = 0u; }  // reset every call
  }

  const size_t gb = ((size_t)b * 32 * 128 + h) * 256;
  #pragma unroll
  for (int s = 0; s < 2; ++s) {
    int task = s * 512 + tid;           // 0..1023
    int cp = task >> 6, w4 = (task & 63) * 4;
    const float* la = lf + gb + (size_t)(2 * cp) * 32768 + w4;
    const float* ra = rf + gb + (size_t)(2 * cp) * 32768 + w4;
    f32x4 va = *reinterpret_cast<const f32x4*>(la);
    f32x4 vb = *reinterpret_cast<const f32x4*>(la + 32768);
    f32x4 wa = *reinterpret_cast<const f32x4*>(ra);
    f32x4 wb = *reinterpret_cast<const f32x4*>(ra + 32768);
    u32x4 lo, ro;
    #pragma unroll
    for (int e = 0; e < 4; ++e) {
      lo[e] = pk2u(__builtin_amdgcn_cvt_pkrtz(va[e], vb[e]));
      ro[e] = pk2u(__builtin_amdgcn_cvt_pkrtz(wa[e], wb[e]));
    }
    *reinterpret_cast<u32x4*>(&lfp[cp * 256 + w4]) = lo;
    *reinterpret_cast<u32x4*>(&rfp[cp * 272 + 16 + w4]) = ro;
  }
  __syncthreads();

  const int wl = lane & 15, dh = lane >> 4;
  u16* rowbase = cost + ((size_t)(b * 128 + h)) * 49152;
  const h2 ones = (h2){(_Float16)1.f, (_Float16)1.f};

  #pragma unroll 1
  for (int ti = q; ti < 48; ti += 8) {
    const int wq = ti / 12, dblk = ti - wq * 12;   // wave-uniform
    const int w0 = wq * 64 + wl * 4;
    const int d0 = dblk * 16 + dh * 4;
    u16* obase = rowbase + dblk * 4096 + dh * 4;

    if (wq * 64 + 63 < dblk * 16) {
      u16x4 z; z[0] = 0; z[1] = 0; z[2] = 0; z[3] = 0;
      #pragma unroll
      for (int j = 0; j < 4; ++j)
        *reinterpret_cast<u16x4*>(obase + (w0 + j) * 16) = z;
      continue;
    }

    float acc[4][4];
    #pragma unroll
    for (int dd = 0; dd < 4; ++dd)
      #pragma unroll
      for (int j = 0; j < 4; ++j) acc[dd][j] = 0.f;

    const u32* lrow = lfp + w0;
    const u32* wrow = rfp + 16 + w0 - d0 - 4;

    #pragma unroll 2
    for (int cp = 0; cp < 16; ++cp) {
      u32x4 lv = *reinterpret_cast<const u32x4*>(lrow + cp * 256);
      u32x4 wA = *reinterpret_cast<const u32x4*>(wrow + cp * 272);
      u32x4 wB = *reinterpret_cast<const u32x4*>(wrow + cp * 272 + 4);
      u32 win8[8];
      #pragma unroll
      for (int e = 0; e < 4; ++e) { win8[e] = wA[e]; win8[4 + e] = wB[e]; }
      #pragma unroll
      for (int dd = 0; dd < 4; ++dd)
        #pragma unroll
        for (int j = 0; j < 4; ++j) {
          h2 diff = u2h2(lv[j]) - u2h2(win8[4 + j - dd]);
          u32 ad = h22u(diff) & 0x7FFF7FFFu;
          acc[dd][j] = __builtin_amdgcn_fdot2(u2h2(ad), ones, acc[dd][j], false);
        }
    }

    #pragma unroll
    for (int j = 0; j < 4; ++j) {
      u16x4 pk;
      #pragma unroll
      for (int dd = 0; dd < 4; ++dd) {
        float v = acc[dd][j] * (1.f / 32.f);
        pk[dd] = (w0 + j >= d0 + dd) ? f2h(v) : (u16)0;
      }
      *reinterpret_cast<u16x4*>(obase + (w0 + j) * 16) = pk;
    }
  }
}

// ---------------- MFMA implicit-GEMM 3x3 conv (4 output rows / block) ----------------
// TRI: cost volume is zero for w < d. Wave M-tiles are w-INTERLEAVED
// (w0 = hf*16 + mf*32) so skipped frags (hf+2mf+1 < cg) split 30/25 across
// the hf wave pair instead of 52/3 -- round-13's hf-major tiling gave the
// skip only to hf=0 waves and the barrier absorbed it.
// FIN (always on): last-finishing block reduces the BN partials and writes
// bn params inline (device-scope fence + ws counter), removing the cv_fin
// kernels + their launch gaps. Counter zeroed each call by cv_cost's prep.
template<int OCB, int HALVES, bool TRANS, bool TRI>
__global__ __launch_bounds__(512, 4) void cv_convm(
    const u16* __restrict__ act, const u16* __restrict__ wre,
    const float* __restrict__ bias, const float* __restrict__ bnp,
    u16* __restrict__ yout, float* __restrict__ ps, float* __restrict__ pq,
    int NCG, const float* __restrict__ gam, const float* __restrict__ beta,
    float* __restrict__ bnout, u32* __restrict__ dcnt, int nblk)
{
  constexpr int NF = OCB / 16;
  constexpr int OCT = OCB * HALVES;
  constexpr int NFT = OCT / 16;

  __shared__ __align__(16) u16 at[6 * 258 * 16];   // 49.5 KB
  __shared__ float reds[8][OCB];
  __shared__ float redq[8][OCB];
  __shared__ int lflag;

  const int tid = threadIdx.x;
  int rp, b, half;
  if (HALVES == 2) {
    int lin = blockIdx.x + 64 * blockIdx.y;      // 0..511
    half = (lin >> 3) & 1;                       // pair (k, k+8): same XCD
    int idx = (lin & 7) | ((lin >> 4) << 3);     // 0..255
    rp = idx & 31; b = idx >> 5;
  } else {
    rp = blockIdx.x; b = blockIdx.y; half = 0;
  }
  const int h0 = rp * 4;
  const int q = tid >> 6, lane = tid & 63;
  const int lanelo = lane & 15, lanehi = lane >> 4;
  const int selB = lane >> 5;
  const int dcb = (lanehi & 1) * 8;
  const int r = q >> 1, hf = q & 1;              // wave -> (out row, w group)
  const int wt0 = TRI ? (hf * 16) : (hf * 128);  // interleaved vs half-major
  const int mstr = TRI ? 512 : 256;              // u16 stride per mf tile

  if (tid < 192) {
    int row = tid >> 5, side = (tid >> 4) & 1, dc = tid & 15;
    at[(row * 258 + side * 257) * 16 + dc] = 0;
  }

  f32x4 acc[8][NF];
  #pragma unroll
  for (int mf = 0; mf < 8; ++mf)
    #pragma unroll
    for (int nf = 0; nf < NF; ++nf)
      acc[mf][nf] = (f32x4){0.f, 0.f, 0.f, 0.f};

  const int dc0t = (tid & 1) * 8;   // TRANS: channel sub-offset of this chunk

  #pragma unroll 1
  for (int cg = 0; cg < NCG; ++cg) {
    if constexpr (!TRANS) {
      #pragma unroll
      for (int row = 0; row < 6; ++row) {
        int hsrc = h0 - 1 + row;
        if (hsrc >= 0 && hsrc < 128) {
          gl_lds16(act + ((size_t)((b * 128 + hsrc) * NCG + cg)) * 4096 + tid * 8,
                   &at[(row * 258 + 1) * 16 + q * 512]);
        } else {
          u16x8 z;
          #pragma unroll
          for (int j = 0; j < 8; ++j) z[j] = 0;
          *reinterpret_cast<u16x8*>(&at[(row * 258 + 1) * 16 + tid * 8]) = z;
        }
      }
    } else {
      float av[8], bv[8];
      #pragma unroll
      for (int j = 0; j < 8; ++j) {
        av[j] = bnp[cg * 16 + dc0t + j];
        bv[j] = bnp[NCG * 16 + cg * 16 + dc0t + j];
      }
      #pragma unroll
      for (int row = 0; row < 6; ++row) {
        int hsrc = h0 - 1 + row;
        u16x8 tv;
        if (hsrc >= 0 && hsrc < 128) {
          u16x8 raw = *reinterpret_cast<const u16x8*>(
              act + ((size_t)((b * 128 + hsrc) * NCG + cg)) * 4096 + tid * 8);
          #pragma unroll
          for (int j = 0; j < 8; ++j)
            tv[j] = f2h(fmaxf(fmaf(h2f(raw[j]), av[j], bv[j]), 0.f));
        } else {
          #pragma unroll
          for (int j = 0; j < 8; ++j) tv[j] = 0;
        }
        *reinterpret_cast<u16x8*>(&at[(row * 258 + 1) * 16 + tid * 8]) = tv;
      }
    }
    __syncthreads();

    const u16* wsrcg = wre + (size_t)cg * (5 * OCT * 32);
    #pragma unroll
    for (int s = 0; s < 5; ++s) {
      const int tA = 2 * s, tB = (2 * s + 1 < 9) ? (2 * s + 1) : 8;
      const int khA = tA / 3, kwA = tA % 3;
      const int khB = tB / 3, kwB = tB % 3;
      const int kh = selB ? khB : khA;
      const int kw = selB ? kwB : kwA;
      h8 bfr[NF];
      #pragma unroll
      for (int nf = 0; nf < NF; ++nf)
        bfr[nf] = *reinterpret_cast<const h8*>(
            wsrcg + (s * OCT + half * OCB + nf * 16 + lanelo) * 32 + lanehi * 8);
      const int abase = ((r + kh) * 258 + wt0 + lanelo + kw) * 16 + dcb;
      #pragma unroll
      for (int mf = 0; mf < 8; ++mf) {
        if (!TRI || (hf + 2 * mf + 1 >= cg)) {
          h8 a = *reinterpret_cast<const h8*>(&at[abase + mf * mstr]);
          #pragma unroll
          for (int nf = 0; nf < NF; ++nf)
            acc[mf][nf] = __builtin_amdgcn_mfma_f32_16x16x32_f16(a, bfr[nf], acc[mf][nf], 0, 0, 0);
        }
      }
    }
    __syncthreads();
  }

  // ---- epilogue: bias, BN partial stats, transposed store ----
  #pragma unroll
  for (int nf = 0; nf < NF; ++nf) {
    float bv = bias[half * OCB + nf * 16 + lanelo];
    #pragma unroll
    for (int mf = 0; mf < 8; ++mf)
      #pragma unroll
      for (int e = 0; e < 4; ++e)
        acc[mf][nf][e] += bv;
  }

  float s_[NF], qq[NF];
  #pragma unroll
  for (int nf = 0; nf < NF; ++nf) {
    s_[nf] = 0.f; qq[nf] = 0.f;
    #pragma unroll
    for (int mf = 0; mf < 8; ++mf)
      #pragma unroll
      for (int e = 0; e < 4; ++e) {
        float v = acc[mf][nf][e];
        s_[nf] += v; qq[nf] += v * v;
      }
  }
  #pragma unroll
  for (int nf = 0; nf < NF; ++nf) {
    s_[nf] += __shfl_xor(s_[nf], 16, 64);
    s_[nf] += __shfl_xor(s_[nf], 32, 64);
    qq[nf] += __shfl_xor(qq[nf], 16, 64);
    qq[nf] += __shfl_xor(qq[nf], 32, 64);
  }
  if (lanehi == 0) {
    #pragma unroll
    for (int nf = 0; nf < NF; ++nf) {
      reds[q][nf * 16 + lanelo] = s_[nf];
      redq[q][nf * 16 + lanelo] = qq[nf];
    }
  }
  __syncthreads();
  if (tid < OCB) {
    int bid = b * 32 + rp;                       // 256 partials
    float ss = 0.f, sq = 0.f;
    #pragma unroll
    for (int w = 0; w < 8; ++w) { ss += reds[w][tid]; sq += redq[w][tid]; }
    ps[bid * OCT + half * OCB + tid] = ss;
    pq[bid * OCT + half * OCB + tid] = sq;
  }

  u16* eb = at;  // reuse: [1024 px][16 oc] = 32 KB
  #pragma unroll
  for (int nf = 0; nf < NF; ++nf) {
    __syncthreads();
    #pragma unroll
    for (int mf = 0; mf < 8; ++mf)
      #pragma unroll
      for (int e = 0; e < 4; ++e) {
        int px = r * 256 + (TRI ? (hf * 16 + mf * 32) : (hf * 128 + mf * 16))
               + lanehi * 4 + e;
        eb[px * 16 + lanelo] = f2h(acc[mf][nf][e]);
      }
    __syncthreads();
    #pragma unroll
    for (int j = 0; j < 4; ++j) {
      int c = j * 512 + tid;          // 2048 chunks of 8 u16
      int px = c >> 1, sub = (c & 1) * 8;
      int row = px >> 8, wpos = px & 255;
      u16x8 v = *reinterpret_cast<const u16x8*>(&eb[c * 8]);
      *reinterpret_cast<u16x8*>(
          yout + ((size_t)((b * 128 + h0 + row) * NFT + half * NF + nf)) * 4096
               + wpos * 16 + sub) = v;
    }
  }

  // ---- inline BN finalize: last block to finish reduces all partials ----
  __threadfence();                 // make this block's ps/pq device-visible
  __syncthreads();                 // all threads' fences complete
  if (tid == 0)
    lflag = (atomicAdd(dcnt, 1u) == (u32)(nblk - 1)) ? 1 : 0;
  __syncthreads();
  if (lflag) {
    __threadfence();               // acquire: see all blocks' partials
    float* fs = (float*)at;        // scratch: [CH][OCT] sums | +4096 sq
    constexpr int CH = 512 / OCT;
    int o = tid & (OCT - 1), ch = tid / OCT;
    float s = 0.f, qv = 0.f;
    for (int k = ch; k < 256; k += CH) { s += ps[k * OCT + o]; qv += pq[k * OCT + o]; }
    fs[ch * OCT + o] = s;
    fs[4096 + ch * OCT + o] = qv;
    __syncthreads();
    if (tid < OCT) {
      float ss = 0.f, sq = 0.f;
      #pragma unroll
      for (int w = 0; w < CH; ++w) { ss += fs[w * OCT + tid]; sq += fs[4096 + w * OCT + tid]; }
      float inv = 1.f / 262144.f;
      float mean = ss * inv;
      float var = sq * inv - mean * mean;
      float a = gam[tid] * rsqrtf(var + 1e-5f);
      bnout[tid] = a;
      bnout[OCT + tid] = beta[tid] - mean * a;
    }
  }
}

// ---------------- deconv (vectorized u32x4 act loads + packed f16 math) ----------------
__global__ __launch_bounds__(512) void cv_deconv(
    const u16* __restrict__ y2, const float* __restrict__ bn2,
    const u16* __restrict__ wdt, const float* __restrict__ db,
    float* __restrict__ out)
{
  __shared__ __align__(16) u16 wl[512];   // [tap16][c32] f16
  const int tid = threadIdx.x;
  wl[tid] = wdt[tid];
  __syncthreads();

  const int i = blockIdx.x;    // 0..127
  const int b = blockIdx.y;
  const int ow = tid;

  u32 bna[16], bns[16];
  #pragma unroll
  for (int p = 0; p < 16; ++p) {
    bna[p] = pk2u(__builtin_amdgcn_cvt_pkrtz(bn2[2 * p], bn2[2 * p + 1]));
    bns[p] = pk2u(__builtin_amdgcn_cvt_pkrtz(bn2[32 + 2 * p], bn2[32 + 2 * p + 1]));
  }

  const int rp = (ow + 1) & 1;
  const int iwA = (ow + 1 - rp) >> 1;   // kw = rp
  const h2 hzero = (h2){(_Float16)0.f, (_Float16)0.f};
  float res[2];
  res[0] = db[0]; res[1] = db[0];

  #pragma unroll
  for (int os = 0; os < 2; ++os) {
    const int oh = 2 * i + os;
    const int kh0 = (oh + 1) & 1;
    #pragma unroll
    for (int t = 0; t < 2; ++t) {
      const int kh = kh0 + 2 * t;
      const int ih = (oh + 1 - kh) >> 1;
      if (ih < 0 || ih >= 128) continue;
      #pragma unroll
      for (int u = 0; u < 2; ++u) {
        const int kw = rp + 2 * u;
        const int iw = iwA - u;
        if (iw < 0 || iw >= 256) continue;
        const int tap = kh * 4 + kw;
        const u16* abase = y2 + ((size_t)(b * 128 + ih) * 2) * 4096 + iw * 16;
        #pragma unroll
        for (int cg = 0; cg < 2; ++cg) {
          u32x4 av0 = *reinterpret_cast<const u32x4*>(abase + cg * 4096);
          u32x4 av1 = *reinterpret_cast<const u32x4*>(abase + cg * 4096 + 8);
          u32x4 wv0 = *reinterpret_cast<const u32x4*>(&wl[tap * 32 + cg * 16]);
          u32x4 wv1 = *reinterpret_cast<const u32x4*>(&wl[tap * 32 + cg * 16 + 8]);
          #pragma unroll
          for (int k = 0; k < 4; ++k) {
            h2 x0 = u2h2(av0[k]) * u2h2(bna[cg * 8 + k]) + u2h2(bns[cg * 8 + k]);
            x0 = __builtin_elementwise_max(x0, hzero);
            res[os] = __builtin_amdgcn_fdot2(x0, u2h2(wv0[k]), res[os], false);
            h2 x1 = u2h2(av1[k]) * u2h2(bna[cg * 8 + 4 + k]) + u2h2(bns[cg * 8 + 4 + k]);
            x1 = __builtin_elementwise_max(x1, hzero);
            res[os] = __builtin_amdgcn_fdot2(x1, u2h2(wv1[k]), res[os], false);
          }
        }
      }
    }
    out[(size_t)(b * 256 + oh) * 512 + ow] = res[os];
  }
}

// ---------------- launcher (4 dispatches) ----------------
extern "C" void kernel_launch(void* const* d_in, const int* in_sizes, int n_in,
                              void* d_out, int out_size, void* d_ws, size_t ws_size,
                              hipStream_t stream)
{
  const float* lf  = (const float*)d_in[0];
  const float* rf  = (const float*)d_in[1];
  const float* w1  = (const float*)d_in[2];
  const float* b1  = (const float*)d_in[3];
  const float* g1  = (const float*)d_in[4];
  const float* be1 = (const float*)d_in[5];
  const float* w2  = (const float*)d_in[6];
  const float* b2  = (const float*)d_in[7];
  const float* g2  = (const float*)d_in[8];
  const float* be2 = (const float*)d_in[9];
  const float* wdc = (const float*)d_in[10];
  const float* dbc = (const float*)d_in[11];
  float* out = (float*)d_out;

  char* ws = (char*)d_ws;
  u16* cost  = (u16*)(ws + OFF_COST);
  u16* y1    = (u16*)(ws + OFF_Y1);
  u16* y2    = (u16*)(ws + OFF_Y2);
  u16* w1s   = (u16*)(ws + OFF_W1S);
  u16* w2s   = (u16*)(ws + OFF_W2S);
  float* p1s = (float*)(ws + OFF_P1S);
  float* p1q = (float*)(ws + OFF_P1Q);
  float* p2s = (float*)(ws + OFF_P2S);
  float* p2q = (float*)(ws + OFF_P2Q);
  float* bn1 = (float*)(ws + OFF_BN1);
  float* bn2 = (float*)(ws + OFF_BN2);
  u16* wdt   = (u16*)(ws + OFF_WDT);
  u32* cnt   = (u32*)(ws + OFF_CNT);

  cv_cost<<<dim3(128, 8), dim3(512), 0, stream>>>(
      lf, rf, cost, w1, w2, wdc, w1s, w2s, wdt, cnt);
  cv_convm<32, 2, false, true><<<dim3(64, 8), dim3(512), 0, stream>>>(
      cost, w1s, b1, nullptr, y1, p1s, p1q, 12, g1, be1, bn1, cnt + 0, 512);
  cv_convm<32, 1, true, false><<<dim3(32, 8), dim3(512), 0, stream>>>(
      y1, w2s, b2, bn1, y2, p2s, p2q, 4, g2, be2, bn2, cnt + 1, 256);
  cv_deconv<<<dim3(128, 8), dim3(512), 0, stream>>>(y2, bn2, wdt, dbc, out);
}

// Round 15
// 176.824 us; speedup vs baseline: 1.9522x; 1.9522x over previous
//
#include <hip/hip_runtime.h>

typedef unsigned short u16;
typedef unsigned int u32;
typedef __attribute__((ext_vector_type(4))) u16 u16x4;
typedef __attribute__((ext_vector_type(8))) u16 u16x8;
typedef __attribute__((ext_vector_type(4))) u32 u32x4;
typedef __attribute__((ext_vector_type(4))) float f32x4;
typedef __attribute__((ext_vector_type(8))) _Float16 h8;
typedef __attribute__((ext_vector_type(2))) _Float16 h2;
typedef __attribute__((ext_vector_type(2))) __fp16 fp16x2;  // cvt_pkrtz return type

#define DEV static __device__ __forceinline__

DEV u16 f2h(float f) {
  union { _Float16 h; u16 u; } v; v.h = (_Float16)f; return v.u;
}
DEV float h2f(u16 u) {
  union { u16 u; _Float16 h; } v; v.u = u; return (float)v.h;
}
DEV h2 u2h2(u32 x) { union { u32 u; h2 h; } v; v.u = x; return v.h; }
DEV u32 h22u(h2 x) { union { u32 u; h2 h; } v; v.h = x; return v.u; }
DEV u32 pk2u(fp16x2 x) { union { u32 u; fp16x2 h; } v; v.h = x; return v.u; }

DEV void gl_lds16(const void* g, void* l) {
  __builtin_amdgcn_global_load_lds(
      (const __attribute__((address_space(1))) unsigned int*)g,
      (__attribute__((address_space(3))) unsigned int*)l,
      16, 0, 0);
}

// ---------------- workspace layout (bytes) ----------------
static const size_t OFF_COST = 0;
static const size_t OFF_Y1   = 100663296u;
static const size_t OFF_Y2   = 134217728u;
static const size_t OFF_W1S  = 150994944u;
static const size_t OFF_W2S  = 151240704u;
static const size_t OFF_P1S  = 151281664u;   // f32 [256][64]
static const size_t OFF_P1Q  = 151412736u;
static const size_t OFF_P2S  = 151543808u;   // f32 [256][32]
static const size_t OFF_P2Q  = 151609344u;
static const size_t OFF_BN1  = 151674880u;
static const size_t OFF_BN2  = 151675392u;
static const size_t OFF_WDT  = 151675648u;   // f16 [16 tap][32 c]

// NOTE (round-14 lesson): do NOT fold BN finalize into the conv kernels with
// a last-block __threadfence pattern -- device-scope fences on CDNA must
// cross non-coherent XCD L2s (writeback-class), and 512 of them quadrupled
// conv time. Separate tiny fin kernels are ~2us each.

// ---------------- weight reorder + f16 convert ----------------
__global__ void cv_prep(const float* __restrict__ w1, const float* __restrict__ w2,
                        const float* __restrict__ wd,
                        u16* __restrict__ w1s, u16* __restrict__ w2s,
                        u16* __restrict__ wdt)
{
  int i = blockIdx.x * 256 + threadIdx.x;
  if (i < 122880) {
    int k = i & 31, o = (i >> 5) & 63;
    int s = (i >> 11) % 5, cg = (i >> 11) / 5;
    int slot = k >> 4, dc = k & 15;
    int tap = 2 * s + slot;
    float v = 0.f;
    if (tap < 9) {
      int kh = tap / 3, kw = tap % 3;
      int c = cg * 16 + dc;
      v = w1[((o * 192 + c) * 3 + kh) * 3 + kw];
    }
    w1s[i] = f2h(v);
  }
  if (i < 20480) {
    int k = i & 31, o = (i >> 5) & 31;
    int s = (i >> 10) % 5, cg = (i >> 10) / 5;
    int slot = k >> 4, dc = k & 15;
    int tap = 2 * s + slot;
    float v = 0.f;
    if (tap < 9) {
      int kh = tap / 3, kw = tap % 3;
      int c = cg * 16 + dc;
      v = w2[((o * 64 + c) * 3 + kh) * 3 + kw];
    }
    w2s[i] = f2h(v);
  }
  if (i < 512) {
    int tap = i >> 5, c = i & 31;    // wdt[tap][c] = wd[c][tap]
    wdt[i] = f2h(wd[c * 16 + tap]);
  }
}

// ---------------- cost volume: triangle-skipped 16d x 64w tiles ----------------
__global__ __launch_bounds__(512, 4) void cv_cost(const float* __restrict__ lf,
                                                  const float* __restrict__ rf,
                                                  u16* __restrict__ cost)
{
  __shared__ __align__(16) u32 smem[16 * 256 + 16 * 272];  // lfp | rfp
  u32* lfp = smem;
  u32* rfp = smem + 16 * 256;

  const int tid = threadIdx.x;
  const int lane = tid & 63, q = tid >> 6;   // q in 0..7
  const int h = blockIdx.x, b = blockIdx.y;

  const size_t gb = ((size_t)b * 32 * 128 + h) * 256;
  #pragma unroll
  for (int s = 0; s < 2; ++s) {
    int task = s * 512 + tid;           // 0..1023
    int cp = task >> 6, w4 = (task & 63) * 4;
    const float* la = lf + gb + (size_t)(2 * cp) * 32768 + w4;
    const float* ra = rf + gb + (size_t)(2 * cp) * 32768 + w4;
    f32x4 va = *reinterpret_cast<const f32x4*>(la);
    f32x4 vb = *reinterpret_cast<const f32x4*>(la + 32768);
    f32x4 wa = *reinterpret_cast<const f32x4*>(ra);
    f32x4 wb = *reinterpret_cast<const f32x4*>(ra + 32768);
    u32x4 lo, ro;
    #pragma unroll
    for (int e = 0; e < 4; ++e) {
      lo[e] = pk2u(__builtin_amdgcn_cvt_pkrtz(va[e], vb[e]));
      ro[e] = pk2u(__builtin_amdgcn_cvt_pkrtz(wa[e], wb[e]));
    }
    *reinterpret_cast<u32x4*>(&lfp[cp * 256 + w4]) = lo;
    *reinterpret_cast<u32x4*>(&rfp[cp * 272 + 16 + w4]) = ro;
  }
  __syncthreads();

  const int wl = lane & 15, dh = lane >> 4;
  u16* rowbase = cost + ((size_t)(b * 128 + h)) * 49152;
  const h2 ones = (h2){(_Float16)1.f, (_Float16)1.f};

  #pragma unroll 1
  for (int ti = q; ti < 48; ti += 8) {
    const int wq = ti / 12, dblk = ti - wq * 12;   // wave-uniform
    const int w0 = wq * 64 + wl * 4;
    const int d0 = dblk * 16 + dh * 4;
    u16* obase = rowbase + dblk * 4096 + dh * 4;

    if (wq * 64 + 63 < dblk * 16) {
      u16x4 z; z[0] = 0; z[1] = 0; z[2] = 0; z[3] = 0;
      #pragma unroll
      for (int j = 0; j < 4; ++j)
        *reinterpret_cast<u16x4*>(obase + (w0 + j) * 16) = z;
      continue;
    }

    float acc[4][4];
    #pragma unroll
    for (int dd = 0; dd < 4; ++dd)
      #pragma unroll
      for (int j = 0; j < 4; ++j) acc[dd][j] = 0.f;

    const u32* lrow = lfp + w0;
    const u32* wrow = rfp + 16 + w0 - d0 - 4;

    #pragma unroll 2
    for (int cp = 0; cp < 16; ++cp) {
      u32x4 lv = *reinterpret_cast<const u32x4*>(lrow + cp * 256);
      u32x4 wA = *reinterpret_cast<const u32x4*>(wrow + cp * 272);
      u32x4 wB = *reinterpret_cast<const u32x4*>(wrow + cp * 272 + 4);
      u32 win8[8];
      #pragma unroll
      for (int e = 0; e < 4; ++e) { win8[e] = wA[e]; win8[4 + e] = wB[e]; }
      #pragma unroll
      for (int dd = 0; dd < 4; ++dd)
        #pragma unroll
        for (int j = 0; j < 4; ++j) {
          h2 diff = u2h2(lv[j]) - u2h2(win8[4 + j - dd]);
          u32 ad = h22u(diff) & 0x7FFF7FFFu;
          acc[dd][j] = __builtin_amdgcn_fdot2(u2h2(ad), ones, acc[dd][j], false);
        }
    }

    #pragma unroll
    for (int j = 0; j < 4; ++j) {
      u16x4 pk;
      #pragma unroll
      for (int dd = 0; dd < 4; ++dd) {
        float v = acc[dd][j] * (1.f / 32.f);
        pk[dd] = (w0 + j >= d0 + dd) ? f2h(v) : (u16)0;
      }
      *reinterpret_cast<u16x4*>(obase + (w0 + j) * 16) = pk;
    }
  }
}

// ---------------- MFMA implicit-GEMM 3x3 conv (4 output rows / block) ----------------
// TRI: cost volume is zero for w < d. Wave M-tiles are w-INTERLEAVED
// (w0 = hf*16 + mf*32) so skipped frags (hf+2mf+1 < cg) split 30/25 across
// the hf wave pair (round-13's hf-major split was 52/3 and the barrier
// absorbed the saving). Bit-identical output; bank pattern of A-reads
// unchanged (mf term is wave-uniform).
template<int OCB, int HALVES, bool TRANS, bool TRI>
__global__ __launch_bounds__(512, 4) void cv_convm(
    const u16* __restrict__ act, const u16* __restrict__ wre,
    const float* __restrict__ bias, const float* __restrict__ bnp,
    u16* __restrict__ yout, float* __restrict__ ps, float* __restrict__ pq,
    int NCG)
{
  constexpr int NF = OCB / 16;
  constexpr int OCT = OCB * HALVES;
  constexpr int NFT = OCT / 16;

  __shared__ __align__(16) u16 at[6 * 258 * 16];   // 49.5 KB
  __shared__ float reds[8][OCB];
  __shared__ float redq[8][OCB];

  const int tid = threadIdx.x;
  int rp, b, half;
  if (HALVES == 2) {
    int lin = blockIdx.x + 64 * blockIdx.y;      // 0..511
    half = (lin >> 3) & 1;                       // pair (k, k+8): same XCD
    int idx = (lin & 7) | ((lin >> 4) << 3);     // 0..255
    rp = idx & 31; b = idx >> 5;
  } else {
    rp = blockIdx.x; b = blockIdx.y; half = 0;
  }
  const int h0 = rp * 4;
  const int q = tid >> 6, lane = tid & 63;
  const int lanelo = lane & 15, lanehi = lane >> 4;
  const int selB = lane >> 5;
  const int dcb = (lanehi & 1) * 8;
  const int r = q >> 1, hf = q & 1;              // wave -> (out row, w group)
  const int wt0 = TRI ? (hf * 16) : (hf * 128);  // interleaved vs half-major
  const int mstr = TRI ? 512 : 256;              // u16 stride per mf tile

  if (tid < 192) {
    int row = tid >> 5, side = (tid >> 4) & 1, dc = tid & 15;
    at[(row * 258 + side * 257) * 16 + dc] = 0;
  }

  f32x4 acc[8][NF];
  #pragma unroll
  for (int mf = 0; mf < 8; ++mf)
    #pragma unroll
    for (int nf = 0; nf < NF; ++nf)
      acc[mf][nf] = (f32x4){0.f, 0.f, 0.f, 0.f};

  const int dc0t = (tid & 1) * 8;   // TRANS: channel sub-offset of this chunk

  #pragma unroll 1
  for (int cg = 0; cg < NCG; ++cg) {
    if constexpr (!TRANS) {
      #pragma unroll
      for (int row = 0; row < 6; ++row) {
        int hsrc = h0 - 1 + row;
        if (hsrc >= 0 && hsrc < 128) {
          gl_lds16(act + ((size_t)((b * 128 + hsrc) * NCG + cg)) * 4096 + tid * 8,
                   &at[(row * 258 + 1) * 16 + q * 512]);
        } else {
          u16x8 z;
          #pragma unroll
          for (int j = 0; j < 8; ++j) z[j] = 0;
          *reinterpret_cast<u16x8*>(&at[(row * 258 + 1) * 16 + tid * 8]) = z;
        }
      }
    } else {
      float av[8], bv[8];
      #pragma unroll
      for (int j = 0; j < 8; ++j) {
        av[j] = bnp[cg * 16 + dc0t + j];
        bv[j] = bnp[NCG * 16 + cg * 16 + dc0t + j];
      }
      #pragma unroll
      for (int row = 0; row < 6; ++row) {
        int hsrc = h0 - 1 + row;
        u16x8 tv;
        if (hsrc >= 0 && hsrc < 128) {
          u16x8 raw = *reinterpret_cast<const u16x8*>(
              act + ((size_t)((b * 128 + hsrc) * NCG + cg)) * 4096 + tid * 8);
          #pragma unroll
          for (int j = 0; j < 8; ++j)
            tv[j] = f2h(fmaxf(fmaf(h2f(raw[j]), av[j], bv[j]), 0.f));
        } else {
          #pragma unroll
          for (int j = 0; j < 8; ++j) tv[j] = 0;
        }
        *reinterpret_cast<u16x8*>(&at[(row * 258 + 1) * 16 + tid * 8]) = tv;
      }
    }
    __syncthreads();

    const u16* wsrcg = wre + (size_t)cg * (5 * OCT * 32);
    #pragma unroll
    for (int s = 0; s < 5; ++s) {
      const int tA = 2 * s, tB = (2 * s + 1 < 9) ? (2 * s + 1) : 8;
      const int khA = tA / 3, kwA = tA % 3;
      const int khB = tB / 3, kwB = tB % 3;
      const int kh = selB ? khB : khA;
      const int kw = selB ? kwB : kwA;
      h8 bfr[NF];
      #pragma unroll
      for (int nf = 0; nf < NF; ++nf)
        bfr[nf] = *reinterpret_cast<const h8*>(
            wsrcg + (s * OCT + half * OCB + nf * 16 + lanelo) * 32 + lanehi * 8);
      const int abase = ((r + kh) * 258 + wt0 + lanelo + kw) * 16 + dcb;
      #pragma unroll
      for (int mf = 0; mf < 8; ++mf) {
        if (!TRI || (hf + 2 * mf + 1 >= cg)) {
          h8 a = *reinterpret_cast<const h8*>(&at[abase + mf * mstr]);
          #pragma unroll
          for (int nf = 0; nf < NF; ++nf)
            acc[mf][nf] = __builtin_amdgcn_mfma_f32_16x16x32_f16(a, bfr[nf], acc[mf][nf], 0, 0, 0);
        }
      }
    }
    __syncthreads();
  }

  // ---- epilogue: bias, BN partial stats, transposed store ----
  #pragma unroll
  for (int nf = 0; nf < NF; ++nf) {
    float bv = bias[half * OCB + nf * 16 + lanelo];
    #pragma unroll
    for (int mf = 0; mf < 8; ++mf)
      #pragma unroll
      for (int e = 0; e < 4; ++e)
        acc[mf][nf][e] += bv;
  }

  float s_[NF], qq[NF];
  #pragma unroll
  for (int nf = 0; nf < NF; ++nf) {
    s_[nf] = 0.f; qq[nf] = 0.f;
    #pragma unroll
    for (int mf = 0; mf < 8; ++mf)
      #pragma unroll
      for (int e = 0; e < 4; ++e) {
        float v = acc[mf][nf][e];
        s_[nf] += v; qq[nf] += v * v;
      }
  }
  #pragma unroll
  for (int nf = 0; nf < NF; ++nf) {
    s_[nf] += __shfl_xor(s_[nf], 16, 64);
    s_[nf] += __shfl_xor(s_[nf], 32, 64);
    qq[nf] += __shfl_xor(qq[nf], 16, 64);
    qq[nf] += __shfl_xor(qq[nf], 32, 64);
  }
  if (lanehi == 0) {
    #pragma unroll
    for (int nf = 0; nf < NF; ++nf) {
      reds[q][nf * 16 + lanelo] = s_[nf];
      redq[q][nf * 16 + lanelo] = qq[nf];
    }
  }
  __syncthreads();
  if (tid < OCB) {
    int bid = b * 32 + rp;                       // 256 partials
    float ss = 0.f, sq = 0.f;
    #pragma unroll
    for (int w = 0; w < 8; ++w) { ss += reds[w][tid]; sq += redq[w][tid]; }
    ps[bid * OCT + half * OCB + tid] = ss;
    pq[bid * OCT + half * OCB + tid] = sq;
  }

  u16* eb = at;  // reuse: [1024 px][16 oc] = 32 KB
  #pragma unroll
  for (int nf = 0; nf < NF; ++nf) {
    __syncthreads();
    #pragma unroll
    for (int mf = 0; mf < 8; ++mf)
      #pragma unroll
      for (int e = 0; e < 4; ++e) {
        int px = r * 256 + (TRI ? (hf * 16 + mf * 32) : (hf * 128 + mf * 16))
               + lanehi * 4 + e;
        eb[px * 16 + lanelo] = f2h(acc[mf][nf][e]);
      }
    __syncthreads();
    #pragma unroll
    for (int j = 0; j < 4; ++j) {
      int c = j * 512 + tid;          // 2048 chunks of 8 u16
      int px = c >> 1, sub = (c & 1) * 8;
      int row = px >> 8, wpos = px & 255;
      u16x8 v = *reinterpret_cast<const u16x8*>(&eb[c * 8]);
      *reinterpret_cast<u16x8*>(
          yout + ((size_t)((b * 128 + h0 + row) * NFT + half * NF + nf)) * 4096
               + wpos * 16 + sub) = v;
    }
  }
}

// ---------------- finalize BN stats (parallel, 256 threads) ----------------
__global__ __launch_bounds__(256) void cv_fin1(
    const float* __restrict__ p1s, const float* __restrict__ p1q,
    const float* __restrict__ g, const float* __restrict__ be,
    float* __restrict__ bn1)
{
  __shared__ float rs[4][64], rq[4][64];
  int o = threadIdx.x & 63, ch = threadIdx.x >> 6;
  float s = 0.f, q = 0.f;
  #pragma unroll 4
  for (int k = ch; k < 256; k += 4) { s += p1s[k * 64 + o]; q += p1q[k * 64 + o]; }
  rs[ch][o] = s; rq[ch][o] = q;
  __syncthreads();
  if (threadIdx.x < 64) {
    int oo = threadIdx.x;
    s = rs[0][oo] + rs[1][oo] + rs[2][oo] + rs[3][oo];
    q = rq[0][oo] + rq[1][oo] + rq[2][oo] + rq[3][oo];
    float inv = 1.f / 262144.f;
    float mean = s * inv;
    float var = q * inv - mean * mean;
    float a = g[oo] * rsqrtf(var + 1e-5f);
    bn1[oo] = a;
    bn1[64 + oo] = be[oo] - mean * a;
  }
}

__global__ __launch_bounds__(256) void cv_fin2(
    const float* __restrict__ p2s, const float* __restrict__ p2q,
    const float* __restrict__ g, const float* __restrict__ be,
    float* __restrict__ bn2)
{
  __shared__ float rs[8][32], rq[8][32];
  int o = threadIdx.x & 31, ch = threadIdx.x >> 5;
  float s = 0.f, q = 0.f;
  #pragma unroll 4
  for (int k = ch; k < 256; k += 8) { s += p2s[k * 32 + o]; q += p2q[k * 32 + o]; }
  rs[ch][o] = s; rq[ch][o] = q;
  __syncthreads();
  if (threadIdx.x < 32) {
    int oo = threadIdx.x;
    s = 0.f; q = 0.f;
    #pragma unroll
    for (int w = 0; w < 8; ++w) { s += rs[w][oo]; q += rq[w][oo]; }
    float inv = 1.f / 262144.f;
    float mean = s * inv;
    float var = q * inv - mean * mean;
    float a = g[oo] * rsqrtf(var + 1e-5f);
    bn2[oo] = a;
    bn2[32 + oo] = be[oo] - mean * a;
  }
}

// ---------------- deconv (vectorized u32x4 act loads + packed f16 math) ----------------
__global__ __launch_bounds__(512) void cv_deconv(
    const u16* __restrict__ y2, const float* __restrict__ bn2,
    const u16* __restrict__ wdt, const float* __restrict__ db,
    float* __restrict__ out)
{
  __shared__ __align__(16) u16 wl[512];   // [tap16][c32] f16
  const int tid = threadIdx.x;
  wl[tid] = wdt[tid];
  __syncthreads();

  const int i = blockIdx.x;    // 0..127
  const int b = blockIdx.y;
  const int ow = tid;

  u32 bna[16], bns[16];
  #pragma unroll
  for (int p = 0; p < 16; ++p) {
    bna[p] = pk2u(__builtin_amdgcn_cvt_pkrtz(bn2[2 * p], bn2[2 * p + 1]));
    bns[p] = pk2u(__builtin_amdgcn_cvt_pkrtz(bn2[32 + 2 * p], bn2[32 + 2 * p + 1]));
  }

  const int rp = (ow + 1) & 1;
  const int iwA = (ow + 1 - rp) >> 1;   // kw = rp
  const h2 hzero = (h2){(_Float16)0.f, (_Float16)0.f};
  float res[2];
  res[0] = db[0]; res[1] = db[0];

  #pragma unroll
  for (int os = 0; os < 2; ++os) {
    const int oh = 2 * i + os;
    const int kh0 = (oh + 1) & 1;
    #pragma unroll
    for (int t = 0; t < 2; ++t) {
      const int kh = kh0 + 2 * t;
      const int ih = (oh + 1 - kh) >> 1;
      if (ih < 0 || ih >= 128) continue;
      #pragma unroll
      for (int u = 0; u < 2; ++u) {
        const int kw = rp + 2 * u;
        const int iw = iwA - u;
        if (iw < 0 || iw >= 256) continue;
        const int tap = kh * 4 + kw;
        const u16* abase = y2 + ((size_t)(b * 128 + ih) * 2) * 4096 + iw * 16;
        #pragma unroll
        for (int cg = 0; cg < 2; ++cg) {
          u32x4 av0 = *reinterpret_cast<const u32x4*>(abase + cg * 4096);
          u32x4 av1 = *reinterpret_cast<const u32x4*>(abase + cg * 4096 + 8);
          u32x4 wv0 = *reinterpret_cast<const u32x4*>(&wl[tap * 32 + cg * 16]);
          u32x4 wv1 = *reinterpret_cast<const u32x4*>(&wl[tap * 32 + cg * 16 + 8]);
          #pragma unroll
          for (int k = 0; k < 4; ++k) {
            h2 x0 = u2h2(av0[k]) * u2h2(bna[cg * 8 + k]) + u2h2(bns[cg * 8 + k]);
            x0 = __builtin_elementwise_max(x0, hzero);
            res[os] = __builtin_amdgcn_fdot2(x0, u2h2(wv0[k]), res[os], false);
            h2 x1 = u2h2(av1[k]) * u2h2(bna[cg * 8 + 4 + k]) + u2h2(bns[cg * 8 + 4 + k]);
            x1 = __builtin_elementwise_max(x1, hzero);
            res[os] = __builtin_amdgcn_fdot2(x1, u2h2(wv1[k]), res[os], false);
          }
        }
      }
    }
    out[(size_t)(b * 256 + oh) * 512 + ow] = res[os];
  }
}

// ---------------- launcher ----------------
extern "C" void kernel_launch(void* const* d_in, const int* in_sizes, int n_in,
                              void* d_out, int out_size, void* d_ws, size_t ws_size,
                              hipStream_t stream)
{
  const float* lf  = (const float*)d_in[0];
  const float* rf  = (const float*)d_in[1];
  const float* w1  = (const float*)d_in[2];
  const float* b1  = (const float*)d_in[3];
  const float* g1  = (const float*)d_in[4];
  const float* be1 = (const float*)d_in[5];
  const float* w2  = (const float*)d_in[6];
  const float* b2  = (const float*)d_in[7];
  const float* g2  = (const float*)d_in[8];
  const float* be2 = (const float*)d_in[9];
  const float* wdc = (const float*)d_in[10];
  const float* dbc = (const float*)d_in[11];
  float* out = (float*)d_out;

  char* ws = (char*)d_ws;
  u16* cost  = (u16*)(ws + OFF_COST);
  u16* y1    = (u16*)(ws + OFF_Y1);
  u16* y2    = (u16*)(ws + OFF_Y2);
  u16* w1s   = (u16*)(ws + OFF_W1S);
  u16* w2s   = (u16*)(ws + OFF_W2S);
  float* p1s = (float*)(ws + OFF_P1S);
  float* p1q = (float*)(ws + OFF_P1Q);
  float* p2s = (float*)(ws + OFF_P2S);
  float* p2q = (float*)(ws + OFF_P2Q);
  float* bn1 = (float*)(ws + OFF_BN1);
  float* bn2 = (float*)(ws + OFF_BN2);
  u16* wdt   = (u16*)(ws + OFF_WDT);

  cv_prep<<<dim3(480), dim3(256), 0, stream>>>(w1, w2, wdc, w1s, w2s, wdt);
  cv_cost<<<dim3(128, 8), dim3(512), 0, stream>>>(lf, rf, cost);
  cv_convm<32, 2, false, true><<<dim3(64, 8), dim3(512), 0, stream>>>(
      cost, w1s, b1, nullptr, y1, p1s, p1q, 12);
  cv_fin1<<<dim3(1), dim3(256), 0, stream>>>(p1s, p1q, g1, be1, bn1);
  cv_convm<32, 1, true, false><<<dim3(32, 8), dim3(512), 0, stream>>>(
      y1, w2s, b2, bn1, y2, p2s, p2q, 4);
  cv_fin2<<<dim3(1), dim3(256), 0, stream>>>(p2s, p2q, g2, be2, bn2);
  cv_deconv<<<dim3(128, 8), dim3(512), 0, stream>>>(y2, bn2, wdt, dbc, out);
}

// Round 16
// 173.022 us; speedup vs baseline: 1.9951x; 1.0220x over previous
//
#include <hip/hip_runtime.h>

typedef unsigned short u16;
typedef unsigned int u32;
typedef __attribute__((ext_vector_type(4))) u16 u16x4;
typedef __attribute__((ext_vector_type(8))) u16 u16x8;
typedef __attribute__((ext_vector_type(4))) u32 u32x4;
typedef __attribute__((ext_vector_type(4))) float f32x4;
typedef __attribute__((ext_vector_type(8))) _Float16 h8;
typedef __attribute__((ext_vector_type(2))) _Float16 h2;
typedef __attribute__((ext_vector_type(2))) __fp16 fp16x2;  // cvt_pkrtz return type

#define DEV static __device__ __forceinline__

DEV u16 f2h(float f) {
  union { _Float16 h; u16 u; } v; v.h = (_Float16)f; return v.u;
}
DEV float h2f(u16 u) {
  union { u16 u; _Float16 h; } v; v.u = u; return (float)v.h;
}
DEV h2 u2h2(u32 x) { union { u32 u; h2 h; } v; v.u = x; return v.h; }
DEV u32 h22u(h2 x) { union { u32 u; h2 h; } v; v.h = x; return v.u; }
DEV u32 pk2u(fp16x2 x) { union { u32 u; fp16x2 h; } v; v.h = x; return v.u; }

DEV void gl_lds16(const void* g, void* l) {
  __builtin_amdgcn_global_load_lds(
      (const __attribute__((address_space(1))) unsigned int*)g,
      (__attribute__((address_space(3))) unsigned int*)l,
      16, 0, 0);
}

// ---------------- workspace layout (bytes) ----------------
static const size_t OFF_COST = 0;
static const size_t OFF_Y1   = 100663296u;
static const size_t OFF_Y2   = 134217728u;
static const size_t OFF_W1S  = 150994944u;
static const size_t OFF_W2S  = 151240704u;
static const size_t OFF_P1S  = 151281664u;   // f32 [256][64]
static const size_t OFF_P1Q  = 151412736u;
static const size_t OFF_P2S  = 151543808u;   // f32 [256][32]
static const size_t OFF_P2Q  = 151609344u;
static const size_t OFF_BN1  = 151674880u;
static const size_t OFF_BN2  = 151675392u;
static const size_t OFF_WDT  = 151675648u;   // f16 [16 tap][32 c]

// NOTE (round-14 lesson): do NOT fold BN finalize into the conv kernels with
// a last-block __threadfence pattern -- device-scope fences on CDNA must
// cross non-coherent XCD L2s (writeback-class), and 512 of them quadrupled
// conv time. Separate tiny fin kernels are ~2us each. Prep merge into
// cv_cost is SAFE (outputs consumed by later kernels; stream order suffices).

// ---------------- cost volume (+ merged weight prep) ----------------
// VOP3P (pk/dot2) issues at ~half rate (measured: 3 formulations converge to
// ~3 cyc per element-pair); core = 46us + ~8us overhead = 54us VALU-busy at
// 75us wall. Triangle skip removes 25% of the rectangle. cp-loop unroll 4
// keeps 12 LDS b128 in flight to hide ds_read latency under the chain.
__global__ __launch_bounds__(512, 4) void cv_cost(
    const float* __restrict__ lf, const float* __restrict__ rf,
    u16* __restrict__ cost,
    const float* __restrict__ w1, const float* __restrict__ w2,
    const float* __restrict__ wd,
    u16* __restrict__ w1s, u16* __restrict__ w2s, u16* __restrict__ wdt)
{
  __shared__ __align__(16) u32 smem[16 * 256 + 16 * 272];  // lfp | rfp
  u32* lfp = smem;
  u32* rfp = smem + 16 * 256;

  const int tid = threadIdx.x;
  const int lane = tid & 63, q = tid >> 6;   // q in 0..7
  const int h = blockIdx.x, b = blockIdx.y;

  // ---- merged weight prep (no fences needed: consumed by later kernels) ----
  {
    int gidx = (blockIdx.y * 128 + blockIdx.x) * 512 + tid;
    if (gidx < 122880) {
      int k = gidx & 31, o = (gidx >> 5) & 63;
      int s = (gidx >> 11) % 5, cg = (gidx >> 11) / 5;
      int slot = k >> 4, dc = k & 15;
      int tap = 2 * s + slot;
      float v = 0.f;
      if (tap < 9) {
        int kh = tap / 3, kw = tap % 3;
        int c = cg * 16 + dc;
        v = w1[((o * 192 + c) * 3 + kh) * 3 + kw];
      }
      w1s[gidx] = f2h(v);
    }
    if (gidx < 20480) {
      int k = gidx & 31, o = (gidx >> 5) & 31;
      int s = (gidx >> 10) % 5, cg = (gidx >> 10) / 5;
      int slot = k >> 4, dc = k & 15;
      int tap = 2 * s + slot;
      float v = 0.f;
      if (tap < 9) {
        int kh = tap / 3, kw = tap % 3;
        int c = cg * 16 + dc;
        v = w2[((o * 64 + c) * 3 + kh) * 3 + kw];
      }
      w2s[gidx] = f2h(v);
    }
    if (gidx < 512) {
      int tap = gidx >> 5, c = gidx & 31;    // wdt[tap][c] = wd[c][tap]
      wdt[gidx] = f2h(wd[c * 16 + tap]);
    }
  }

  const size_t gb = ((size_t)b * 32 * 128 + h) * 256;
  #pragma unroll
  for (int s = 0; s < 2; ++s) {
    int task = s * 512 + tid;           // 0..1023
    int cp = task >> 6, w4 = (task & 63) * 4;
    const float* la = lf + gb + (size_t)(2 * cp) * 32768 + w4;
    const float* ra = rf + gb + (size_t)(2 * cp) * 32768 + w4;
    f32x4 va = *reinterpret_cast<const f32x4*>(la);
    f32x4 vb = *reinterpret_cast<const f32x4*>(la + 32768);
    f32x4 wa = *reinterpret_cast<const f32x4*>(ra);
    f32x4 wb = *reinterpret_cast<const f32x4*>(ra + 32768);
    u32x4 lo, ro;
    #pragma unroll
    for (int e = 0; e < 4; ++e) {
      lo[e] = pk2u(__builtin_amdgcn_cvt_pkrtz(va[e], vb[e]));
      ro[e] = pk2u(__builtin_amdgcn_cvt_pkrtz(wa[e], wb[e]));
    }
    *reinterpret_cast<u32x4*>(&lfp[cp * 256 + w4]) = lo;
    *reinterpret_cast<u32x4*>(&rfp[cp * 272 + 16 + w4]) = ro;
  }
  __syncthreads();

  const int wl = lane & 15, dh = lane >> 4;
  u16* rowbase = cost + ((size_t)(b * 128 + h)) * 49152;
  const h2 ones = (h2){(_Float16)1.f, (_Float16)1.f};

  #pragma unroll 1
  for (int ti = q; ti < 48; ti += 8) {
    const int wq = ti / 12, dblk = ti - wq * 12;   // wave-uniform
    const int w0 = wq * 64 + wl * 4;
    const int d0 = dblk * 16 + dh * 4;
    u16* obase = rowbase + dblk * 4096 + dh * 4;

    if (wq * 64 + 63 < dblk * 16) {
      u16x4 z; z[0] = 0; z[1] = 0; z[2] = 0; z[3] = 0;
      #pragma unroll
      for (int j = 0; j < 4; ++j)
        *reinterpret_cast<u16x4*>(obase + (w0 + j) * 16) = z;
      continue;
    }

    float acc[4][4];
    #pragma unroll
    for (int dd = 0; dd < 4; ++dd)
      #pragma unroll
      for (int j = 0; j < 4; ++j) acc[dd][j] = 0.f;

    const u32* lrow = lfp + w0;
    const u32* wrow = rfp + 16 + w0 - d0 - 4;

    #pragma unroll 4
    for (int cp = 0; cp < 16; ++cp) {
      u32x4 lv = *reinterpret_cast<const u32x4*>(lrow + cp * 256);
      u32x4 wA = *reinterpret_cast<const u32x4*>(wrow + cp * 272);
      u32x4 wB = *reinterpret_cast<const u32x4*>(wrow + cp * 272 + 4);
      u32 win8[8];
      #pragma unroll
      for (int e = 0; e < 4; ++e) { win8[e] = wA[e]; win8[4 + e] = wB[e]; }
      #pragma unroll
      for (int dd = 0; dd < 4; ++dd)
        #pragma unroll
        for (int j = 0; j < 4; ++j) {
          h2 diff = u2h2(lv[j]) - u2h2(win8[4 + j - dd]);
          u32 ad = h22u(diff) & 0x7FFF7FFFu;
          acc[dd][j] = __builtin_amdgcn_fdot2(u2h2(ad), ones, acc[dd][j], false);
        }
    }

    #pragma unroll
    for (int j = 0; j < 4; ++j) {
      u16x4 pk;
      #pragma unroll
      for (int dd = 0; dd < 4; ++dd) {
        float v = acc[dd][j] * (1.f / 32.f);
        pk[dd] = (w0 + j >= d0 + dd) ? f2h(v) : (u16)0;
      }
      *reinterpret_cast<u16x4*>(obase + (w0 + j) * 16) = pk;
    }
  }
}

// ---------------- MFMA implicit-GEMM 3x3 conv (4 output rows / block) ----------------
// TRI interleave kept (bit-identical, proven neutral but harmless).
template<int OCB, int HALVES, bool TRANS, bool TRI>
__global__ __launch_bounds__(512, 4) void cv_convm(
    const u16* __restrict__ act, const u16* __restrict__ wre,
    const float* __restrict__ bias, const float* __restrict__ bnp,
    u16* __restrict__ yout, float* __restrict__ ps, float* __restrict__ pq,
    int NCG)
{
  constexpr int NF = OCB / 16;
  constexpr int OCT = OCB * HALVES;
  constexpr int NFT = OCT / 16;

  __shared__ __align__(16) u16 at[6 * 258 * 16];   // 49.5 KB
  __shared__ float reds[8][OCB];
  __shared__ float redq[8][OCB];

  const int tid = threadIdx.x;
  int rp, b, half;
  if (HALVES == 2) {
    int lin = blockIdx.x + 64 * blockIdx.y;      // 0..511
    half = (lin >> 3) & 1;                       // pair (k, k+8): same XCD
    int idx = (lin & 7) | ((lin >> 4) << 3);     // 0..255
    rp = idx & 31; b = idx >> 5;
  } else {
    rp = blockIdx.x; b = blockIdx.y; half = 0;
  }
  const int h0 = rp * 4;
  const int q = tid >> 6, lane = tid & 63;
  const int lanelo = lane & 15, lanehi = lane >> 4;
  const int selB = lane >> 5;
  const int dcb = (lanehi & 1) * 8;
  const int r = q >> 1, hf = q & 1;              // wave -> (out row, w group)
  const int wt0 = TRI ? (hf * 16) : (hf * 128);  // interleaved vs half-major
  const int mstr = TRI ? 512 : 256;              // u16 stride per mf tile

  if (tid < 192) {
    int row = tid >> 5, side = (tid >> 4) & 1, dc = tid & 15;
    at[(row * 258 + side * 257) * 16 + dc] = 0;
  }

  f32x4 acc[8][NF];
  #pragma unroll
  for (int mf = 0; mf < 8; ++mf)
    #pragma unroll
    for (int nf = 0; nf < NF; ++nf)
      acc[mf][nf] = (f32x4){0.f, 0.f, 0.f, 0.f};

  const int dc0t = (tid & 1) * 8;   // TRANS: channel sub-offset of this chunk

  #pragma unroll 1
  for (int cg = 0; cg < NCG; ++cg) {
    if constexpr (!TRANS) {
      #pragma unroll
      for (int row = 0; row < 6; ++row) {
        int hsrc = h0 - 1 + row;
        if (hsrc >= 0 && hsrc < 128) {
          gl_lds16(act + ((size_t)((b * 128 + hsrc) * NCG + cg)) * 4096 + tid * 8,
                   &at[(row * 258 + 1) * 16 + q * 512]);
        } else {
          u16x8 z;
          #pragma unroll
          for (int j = 0; j < 8; ++j) z[j] = 0;
          *reinterpret_cast<u16x8*>(&at[(row * 258 + 1) * 16 + tid * 8]) = z;
        }
      }
    } else {
      float av[8], bv[8];
      #pragma unroll
      for (int j = 0; j < 8; ++j) {
        av[j] = bnp[cg * 16 + dc0t + j];
        bv[j] = bnp[NCG * 16 + cg * 16 + dc0t + j];
      }
      #pragma unroll
      for (int row = 0; row < 6; ++row) {
        int hsrc = h0 - 1 + row;
        u16x8 tv;
        if (hsrc >= 0 && hsrc < 128) {
          u16x8 raw = *reinterpret_cast<const u16x8*>(
              act + ((size_t)((b * 128 + hsrc) * NCG + cg)) * 4096 + tid * 8);
          #pragma unroll
          for (int j = 0; j < 8; ++j)
            tv[j] = f2h(fmaxf(fmaf(h2f(raw[j]), av[j], bv[j]), 0.f));
        } else {
          #pragma unroll
          for (int j = 0; j < 8; ++j) tv[j] = 0;
        }
        *reinterpret_cast<u16x8*>(&at[(row * 258 + 1) * 16 + tid * 8]) = tv;
      }
    }
    __syncthreads();

    const u16* wsrcg = wre + (size_t)cg * (5 * OCT * 32);
    #pragma unroll
    for (int s = 0; s < 5; ++s) {
      const int tA = 2 * s, tB = (2 * s + 1 < 9) ? (2 * s + 1) : 8;
      const int khA = tA / 3, kwA = tA % 3;
      const int khB = tB / 3, kwB = tB % 3;
      const int kh = selB ? khB : khA;
      const int kw = selB ? kwB : kwA;
      h8 bfr[NF];
      #pragma unroll
      for (int nf = 0; nf < NF; ++nf)
        bfr[nf] = *reinterpret_cast<const h8*>(
            wsrcg + (s * OCT + half * OCB + nf * 16 + lanelo) * 32 + lanehi * 8);
      const int abase = ((r + kh) * 258 + wt0 + lanelo + kw) * 16 + dcb;
      #pragma unroll
      for (int mf = 0; mf < 8; ++mf) {
        if (!TRI || (hf + 2 * mf + 1 >= cg)) {
          h8 a = *reinterpret_cast<const h8*>(&at[abase + mf * mstr]);
          #pragma unroll
          for (int nf = 0; nf < NF; ++nf)
            acc[mf][nf] = __builtin_amdgcn_mfma_f32_16x16x32_f16(a, bfr[nf], acc[mf][nf], 0, 0, 0);
        }
      }
    }
    __syncthreads();
  }

  // ---- epilogue: bias, BN partial stats, transposed store ----
  #pragma unroll
  for (int nf = 0; nf < NF; ++nf) {
    float bv = bias[half * OCB + nf * 16 + lanelo];
    #pragma unroll
    for (int mf = 0; mf < 8; ++mf)
      #pragma unroll
      for (int e = 0; e < 4; ++e)
        acc[mf][nf][e] += bv;
  }

  float s_[NF], qq[NF];
  #pragma unroll
  for (int nf = 0; nf < NF; ++nf) {
    s_[nf] = 0.f; qq[nf] = 0.f;
    #pragma unroll
    for (int mf = 0; mf < 8; ++mf)
      #pragma unroll
      for (int e = 0; e < 4; ++e) {
        float v = acc[mf][nf][e];
        s_[nf] += v; qq[nf] += v * v;
      }
  }
  #pragma unroll
  for (int nf = 0; nf < NF; ++nf) {
    s_[nf] += __shfl_xor(s_[nf], 16, 64);
    s_[nf] += __shfl_xor(s_[nf], 32, 64);
    qq[nf] += __shfl_xor(qq[nf], 16, 64);
    qq[nf] += __shfl_xor(qq[nf], 32, 64);
  }
  if (lanehi == 0) {
    #pragma unroll
    for (int nf = 0; nf < NF; ++nf) {
      reds[q][nf * 16 + lanelo] = s_[nf];
      redq[q][nf * 16 + lanelo] = qq[nf];
    }
  }
  __syncthreads();
  if (tid < OCB) {
    int bid = b * 32 + rp;                       // 256 partials
    float ss = 0.f, sq = 0.f;
    #pragma unroll
    for (int w = 0; w < 8; ++w) { ss += reds[w][tid]; sq += redq[w][tid]; }
    ps[bid * OCT + half * OCB + tid] = ss;
    pq[bid * OCT + half * OCB + tid] = sq;
  }

  u16* eb = at;  // reuse: [1024 px][16 oc] = 32 KB
  #pragma unroll
  for (int nf = 0; nf < NF; ++nf) {
    __syncthreads();
    #pragma unroll
    for (int mf = 0; mf < 8; ++mf)
      #pragma unroll
      for (int e = 0; e < 4; ++e) {
        int px = r * 256 + (TRI ? (hf * 16 + mf * 32) : (hf * 128 + mf * 16))
               + lanehi * 4 + e;
        eb[px * 16 + lanelo] = f2h(acc[mf][nf][e]);
      }
    __syncthreads();
    #pragma unroll
    for (int j = 0; j < 4; ++j) {
      int c = j * 512 + tid;          // 2048 chunks of 8 u16
      int px = c >> 1, sub = (c & 1) * 8;
      int row = px >> 8, wpos = px & 255;
      u16x8 v = *reinterpret_cast<const u16x8*>(&eb[c * 8]);
      *reinterpret_cast<u16x8*>(
          yout + ((size_t)((b * 128 + h0 + row) * NFT + half * NF + nf)) * 4096
               + wpos * 16 + sub) = v;
    }
  }
}

// ---------------- finalize BN stats (parallel, 256 threads) ----------------
__global__ __launch_bounds__(256) void cv_fin1(
    const float* __restrict__ p1s, const float* __restrict__ p1q,
    const float* __restrict__ g, const float* __restrict__ be,
    float* __restrict__ bn1)
{
  __shared__ float rs[4][64], rq[4][64];
  int o = threadIdx.x & 63, ch = threadIdx.x >> 6;
  float s = 0.f, q = 0.f;
  #pragma unroll 4
  for (int k = ch; k < 256; k += 4) { s += p1s[k * 64 + o]; q += p1q[k * 64 + o]; }
  rs[ch][o] = s; rq[ch][o] = q;
  __syncthreads();
  if (threadIdx.x < 64) {
    int oo = threadIdx.x;
    s = rs[0][oo] + rs[1][oo] + rs[2][oo] + rs[3][oo];
    q = rq[0][oo] + rq[1][oo] + rq[2][oo] + rq[3][oo];
    float inv = 1.f / 262144.f;
    float mean = s * inv;
    float var = q * inv - mean * mean;
    float a = g[oo] * rsqrtf(var + 1e-5f);
    bn1[oo] = a;
    bn1[64 + oo] = be[oo] - mean * a;
  }
}

__global__ __launch_bounds__(256) void cv_fin2(
    const float* __restrict__ p2s, const float* __restrict__ p2q,
    const float* __restrict__ g, const float* __restrict__ be,
    float* __restrict__ bn2)
{
  __shared__ float rs[8][32], rq[8][32];
  int o = threadIdx.x & 31, ch = threadIdx.x >> 5;
  float s = 0.f, q = 0.f;
  #pragma unroll 4
  for (int k = ch; k < 256; k += 8) { s += p2s[k * 32 + o]; q += p2q[k * 32 + o]; }
  rs[ch][o] = s; rq[ch][o] = q;
  __syncthreads();
  if (threadIdx.x < 32) {
    int oo = threadIdx.x;
    s = 0.f; q = 0.f;
    #pragma unroll
    for (int w = 0; w < 8; ++w) { s += rs[w][oo]; q += rq[w][oo]; }
    float inv = 1.f / 262144.f;
    float mean = s * inv;
    float var = q * inv - mean * mean;
    float a = g[oo] * rsqrtf(var + 1e-5f);
    bn2[oo] = a;
    bn2[32 + oo] = be[oo] - mean * a;
  }
}

// ---------------- deconv (vectorized u32x4 act loads + packed f16 math) ----------------
__global__ __launch_bounds__(512) void cv_deconv(
    const u16* __restrict__ y2, const float* __restrict__ bn2,
    const u16* __restrict__ wdt, const float* __restrict__ db,
    float* __restrict__ out)
{
  __shared__ __align__(16) u16 wl[512];   // [tap16][c32] f16
  const int tid = threadIdx.x;
  wl[tid] = wdt[tid];
  __syncthreads();

  const int i = blockIdx.x;    // 0..127
  const int b = blockIdx.y;
  const int ow = tid;

  u32 bna[16], bns[16];
  #pragma unroll
  for (int p = 0; p < 16; ++p) {
    bna[p] = pk2u(__builtin_amdgcn_cvt_pkrtz(bn2[2 * p], bn2[2 * p + 1]));
    bns[p] = pk2u(__builtin_amdgcn_cvt_pkrtz(bn2[32 + 2 * p], bn2[32 + 2 * p + 1]));
  }

  const int rp = (ow + 1) & 1;
  const int iwA = (ow + 1 - rp) >> 1;   // kw = rp
  const h2 hzero = (h2){(_Float16)0.f, (_Float16)0.f};
  float res[2];
  res[0] = db[0]; res[1] = db[0];

  #pragma unroll
  for (int os = 0; os < 2; ++os) {
    const int oh = 2 * i + os;
    const int kh0 = (oh + 1) & 1;
    #pragma unroll
    for (int t = 0; t < 2; ++t) {
      const int kh = kh0 + 2 * t;
      const int ih = (oh + 1 - kh) >> 1;
      if (ih < 0 || ih >= 128) continue;
      #pragma unroll
      for (int u = 0; u < 2; ++u) {
        const int kw = rp + 2 * u;
        const int iw = iwA - u;
        if (iw < 0 || iw >= 256) continue;
        const int tap = kh * 4 + kw;
        const u16* abase = y2 + ((size_t)(b * 128 + ih) * 2) * 4096 + iw * 16;
        #pragma unroll
        for (int cg = 0; cg < 2; ++cg) {
          u32x4 av0 = *reinterpret_cast<const u32x4*>(abase + cg * 4096);
          u32x4 av1 = *reinterpret_cast<const u32x4*>(abase + cg * 4096 + 8);
          u32x4 wv0 = *reinterpret_cast<const u32x4*>(&wl[tap * 32 + cg * 16]);
          u32x4 wv1 = *reinterpret_cast<const u32x4*>(&wl[tap * 32 + cg * 16 + 8]);
          #pragma unroll
          for (int k = 0; k < 4; ++k) {
            h2 x0 = u2h2(av0[k]) * u2h2(bna[cg * 8 + k]) + u2h2(bns[cg * 8 + k]);
            x0 = __builtin_elementwise_max(x0, hzero);
            res[os] = __builtin_amdgcn_fdot2(x0, u2h2(wv0[k]), res[os], false);
            h2 x1 = u2h2(av1[k]) * u2h2(bna[cg * 8 + 4 + k]) + u2h2(bns[cg * 8 + 4 + k]);
            x1 = __builtin_elementwise_max(x1, hzero);
            res[os] = __builtin_amdgcn_fdot2(x1, u2h2(wv1[k]), res[os], false);
          }
        }
      }
    }
    out[(size_t)(b * 256 + oh) * 512 + ow] = res[os];
  }
}

// ---------------- launcher (6 dispatches) ----------------
extern "C" void kernel_launch(void* const* d_in, const int* in_sizes, int n_in,
                              void* d_out, int out_size, void* d_ws, size_t ws_size,
                              hipStream_t stream)
{
  const float* lf  = (const float*)d_in[0];
  const float* rf  = (const float*)d_in[1];
  const float* w1  = (const float*)d_in[2];
  const float* b1  = (const float*)d_in[3];
  const float* g1  = (const float*)d_in[4];
  const float* be1 = (const float*)d_in[5];
  const float* w2  = (const float*)d_in[6];
  const float* b2  = (const float*)d_in[7];
  const float* g2  = (const float*)d_in[8];
  const float* be2 = (const float*)d_in[9];
  const float* wdc = (const float*)d_in[10];
  const float* dbc = (const float*)d_in[11];
  float* out = (float*)d_out;

  char* ws = (char*)d_ws;
  u16* cost  = (u16*)(ws + OFF_COST);
  u16* y1    = (u16*)(ws + OFF_Y1);
  u16* y2    = (u16*)(ws + OFF_Y2);
  u16* w1s   = (u16*)(ws + OFF_W1S);
  u16* w2s   = (u16*)(ws + OFF_W2S);
  float* p1s = (float*)(ws + OFF_P1S);
  float* p1q = (float*)(ws + OFF_P1Q);
  float* p2s = (float*)(ws + OFF_P2S);
  float* p2q = (float*)(ws + OFF_P2Q);
  float* bn1 = (float*)(ws + OFF_BN1);
  float* bn2 = (float*)(ws + OFF_BN2);
  u16* wdt   = (u16*)(ws + OFF_WDT);

  cv_cost<<<dim3(128, 8), dim3(512), 0, stream>>>(
      lf, rf, cost, w1, w2, wdc, w1s, w2s, wdt);
  cv_convm<32, 2, false, true><<<dim3(64, 8), dim3(512), 0, stream>>>(
      cost, w1s, b1, nullptr, y1, p1s, p1q, 12);
  cv_fin1<<<dim3(1), dim3(256), 0, stream>>>(p1s, p1q, g1, be1, bn1);
  cv_convm<32, 1, true, false><<<dim3(32, 8), dim3(512), 0, stream>>>(
      y1, w2s, b2, bn1, y2, p2s, p2q, 4);
  cv_fin2<<<dim3(1), dim3(256), 0, stream>>>(p2s, p2q, g2, be2, bn2);
  cv_deconv<<<dim3(128, 8), dim3(512), 0, stream>>>(y2, bn2, wdt, dbc, out);
}